// Round 8
// baseline (42.469 us; speedup 1.0000x reference)
//
#include <hip/hip_runtime.h>
#include <math.h>

// Rational-quadratic spline inverse log-prob (Durkan et al.), inverse pass only.
// out = log(0.5) - where(inside, logabsdet, 0)
//
// ws float layout (28,832 B total):
//   edges @ 0    : 8ch x 129 f32 (cumheights; [.,128] = 1+1e-6 sentinel)
//   P4    @ 1032 : 8ch x 129 float4 {h, delta, d0, d1}
//   hint  @ 5160 : 8ch x 1024 u8 (8192 B). slot width 2/1024 = 1.953e-3 < min
//     bin height 2e-3 => at most ONE knot per slot => 1-step fixup exact.
// Per element: 3 LDS ops (u8 hint -> 2x b32 edges -> b128 pack).
// spline_main is SOFTWARE-PIPELINED at float4-group granularity: the LDS
// gather chain for group g+1 is issued before the math of group g (A/B
// register buffers, zero-copy rotation), x prefetched 2-4 groups ahead.

#define NB 128
#define NCH 8
#define NSLOT 1024
#define E_F 0
#define P4_F 1032
#define HINT_F 5160
#define TAB_FLOATS 7208   // 5160 + 8192/4

typedef float v2f __attribute__((ext_vector_type(2)));

__global__ __launch_bounds__(128) void spline_precompute(
    const float* __restrict__ uw, const float* __restrict__ uh,
    const float* __restrict__ ud, float* __restrict__ ws)
{
    const int c = blockIdx.x;   // channel
    const int i = threadIdx.x;  // bin
    __shared__ float red[128];
    __shared__ float scan[128];
    __shared__ float cum[129];
    __shared__ float wdt[128];
    __shared__ float sdv[129];
    const float DEFAULT_INIT = logf(expf(1.0f - 1e-3f) - 1.0f);

    // ---------------- widths: softmax(uw*10) -> sizes -> cumsum -> knots ----
    float v = uw[c * NB + i] * 10.0f;
    red[i] = v; __syncthreads();
    #pragma unroll
    for (int s = 64; s >= 1; s >>= 1) { if (i < s) red[i] = fmaxf(red[i], red[i + s]); __syncthreads(); }
    float ex = expf(v - red[0]);
    __syncthreads();
    red[i] = ex; __syncthreads();
    #pragma unroll
    for (int s = 64; s >= 1; s >>= 1) { if (i < s) red[i] += red[i + s]; __syncthreads(); }
    float sz = 1e-3f + (1.0f - 1e-3f * NB) * (ex / red[0]);
    __syncthreads();
    scan[i] = sz;
    for (int off = 1; off < NB; off <<= 1) {
        __syncthreads();
        float t = (i >= off) ? scan[i - off] : 0.0f;
        __syncthreads();
        scan[i] += t;
    }
    __syncthreads();
    if (i == 0) cum[0] = -1.0f;
    cum[i + 1] = (i == NB - 1) ? 1.0f : fmaf(2.0f, scan[i], -1.0f);
    __syncthreads();
    wdt[i] = cum[i + 1] - cum[i];
    __syncthreads();   // cum gets reused below

    // ---------------- heights: same pipeline on uh*10 ----------------------
    v = uh[c * NB + i] * 10.0f;
    red[i] = v; __syncthreads();
    #pragma unroll
    for (int s = 64; s >= 1; s >>= 1) { if (i < s) red[i] = fmaxf(red[i], red[i + s]); __syncthreads(); }
    ex = expf(v - red[0]);
    __syncthreads();
    red[i] = ex; __syncthreads();
    #pragma unroll
    for (int s = 64; s >= 1; s >>= 1) { if (i < s) red[i] += red[i + s]; __syncthreads(); }
    sz = 1e-3f + (1.0f - 1e-3f * NB) * (ex / red[0]);
    __syncthreads();
    scan[i] = sz;
    for (int off = 1; off < NB; off <<= 1) {
        __syncthreads();
        float t = (i >= off) ? scan[i - off] : 0.0f;
        __syncthreads();
        scan[i] += t;
    }
    __syncthreads();
    if (i == 0) cum[0] = -1.0f;
    cum[i + 1] = (i == NB - 1) ? 1.0f : fmaf(2.0f, scan[i], -1.0f);

    // ---------------- derivatives: MIN_D + softplus(pad(ud)) ---------------
    float u0 = (i == 0) ? DEFAULT_INIT : ud[c * (NB - 1) + i - 1];
    sdv[i] = 1e-3f + log1pf(expf(u0));
    if (i == NB - 1) sdv[NB] = 1e-3f + log1pf(expf(DEFAULT_INIT));
    __syncthreads();

    // ---------------- emit tables ------------------------------------------
    float hh  = cum[i + 1] - cum[i];
    float idl = hh / wdt[i];
    const int o = c * 129 + i;

    ws[E_F + o] = cum[i];
    if (i == NB - 1) ws[E_F + c * 129 + NB] = 1.0f + 1e-6f;   // sentinel
    float4* g_p4 = reinterpret_cast<float4*>(ws + P4_F);
    g_p4[o] = make_float4(hh, idl, sdv[i], sdv[i + 1]);

    // hint[s] = max k in [0,127] with cum[k] <= slot_left  (true bin = k or k+1)
    unsigned char* g_hint = reinterpret_cast<unsigned char*>(ws + HINT_F);
    for (int s = i; s < NSLOT; s += NB) {
        float left = (float)s * (2.0f / NSLOT) - 1.0f;
        int k = 0;
        #pragma unroll
        for (int st = 64; st >= 1; st >>= 1) {   // 64+...+1 = 127, stays in [0,127]
            int t = k + st;
            if (cum[t] <= left) k = t;
        }
        g_hint[c * NSLOT + s] = (unsigned char)k;
    }
}

__global__ __launch_bounds__(256, 4) void spline_main(
    const float4* __restrict__ x4, float4* __restrict__ out4,
    const float* __restrict__ ws, int npair)
{
    __shared__ __align__(16) float tab[TAB_FLOATS];
    {
        float4* dst = reinterpret_cast<float4*>(tab);
        const float4* src = reinterpret_cast<const float4*>(ws);
        for (int t = threadIdx.x; t < TAB_FLOATS / 4; t += 256) dst[t] = src[t];
    }
    __syncthreads();
    const float* eg = tab + E_F;
    const float4* p4 = reinterpret_cast<const float4*>(tab + P4_F);
    const unsigned char* hint = reinterpret_cast<const unsigned char*>(tab + HINT_F);

    const float LOG_HALF = -0.6931471805599453f;
    const float LN2 = 0.6931471805599453f;
    const int tid = blockIdx.x * 256 + threadIdx.x;
    const int stride = gridDim.x * 256;
    const int niter = npair / stride;      // exact (launch config); even
    const int ng = 2 * niter;              // float4 groups per thread

    // group g -> x4/out4 flat index; clamp keeps tail prefetch/gather in-bounds
    auto idx4 = [&](int g) {
        int gg = (g < ng) ? g : 0;
        return 2 * (tid + (gg >> 1) * stride) + (gg & 1);
    };

    // gather chain for one float4 group (channels CB..CB+3)
    auto gather4 = [&](const float4& xv, int CB, float4* pk, float* dy, float* lmf) {
        float xs[4] = {xv.x, xv.y, xv.z, xv.w};
        float xq[4]; int kk[4];
        #pragma unroll
        for (int j = 0; j < 4; ++j) {
            float xc = fminf(fmaxf(xs[j], -1.0f), 1.0f);
            xq[j] = xc;
            int s = (int)fmaf(xc, (float)(NSLOT / 2), (float)(NSLOT / 2));
            s = (s > NSLOT - 1) ? NSLOT - 1 : s;
            kk[j] = hint[(CB + j) * NSLOT + s];
        }
        float e0[4], e1[4];
        #pragma unroll
        for (int j = 0; j < 4; ++j) {
            const float* ej = eg + (CB + j) * 129 + kk[j];
            e0[j] = ej[0];
            e1[j] = ej[1];
        }
        #pragma unroll
        for (int j = 0; j < 4; ++j) {
            bool adv = (e1[j] <= xq[j]);
            int k2 = kk[j] + (adv ? 1 : 0);
            dy[j]  = xq[j] - (adv ? e1[j] : e0[j]);
            lmf[j] = (xs[j] == xq[j]) ? LN2 : 0.0f;   // inside <=> clamp no-op
            pk[j]  = p4[(CB + j) * 129 + k2];
        }
    };

    // packed-f32 math + store for one group
    auto mathstore = [&](const float4* pk, const float* dy4, const float* lmf, int oidx) {
        float rs[4];
        #pragma unroll
        for (int jj = 0; jj < 2; ++jj) {
            v2f h  = {pk[jj].x, pk[jj + 2].x};
            v2f dl = {pk[jj].y, pk[jj + 2].y};
            v2f d0 = {pk[jj].z, pk[jj + 2].z};
            v2f d1 = {pk[jj].w, pk[jj + 2].w};
            v2f dy = {dy4[jj],  dy4[jj + 2]};
            const v2f m2 = {-2.0f, -2.0f};
            const v2f m4 = {-4.0f, -4.0f};
            const v2f zz = {0.0f, 0.0f};

            v2f T    = __builtin_elementwise_fma(m2, dl, d0 + d1);
            v2f dyt  = dy * T;
            v2f B    = h * d0;
            v2f A    = __builtin_elementwise_fma(h, dl, -B);   // h*(dl-d0)
            v2f aa   = dyt + A;
            v2f bb   = B - dyt;
            v2f cc   = -dl * dy;
            v2f ac   = aa * cc;
            v2f disc = __builtin_elementwise_max(
                           __builtin_elementwise_fma(m4, ac, bb * bb), zz);
            v2f sq   = {__builtin_amdgcn_sqrtf(disc.x),
                        __builtin_amdgcn_sqrtf(disc.y)};
            v2f w    = -bb - sq;                    // root = u/w, u = 2c
            v2f u    = cc + cc;
            v2f w2   = w * w;
            v2f tu   = T * u;
            v2f sdd  = dl - d0;
            v2f E    = sdd + sdd;
            v2f t1   = __builtin_elementwise_fma(E, w, tu);    // T*u + E*w
            v2f num  = __builtin_elementwise_fma(t1, u, d0 * w2);
            v2f d2   = dl * dl;
            v2f numf = (num * w2) * d2;
            v2f wmu  = w - u;
            v2f denb = __builtin_elementwise_fma(tu, wmu, dl * w2);
            v2f den2 = denb * denb;

            float va = __fdividef(numf.x, den2.x);
            float vb = __fdividef(numf.y, den2.y);
            rs[jj]     = fmaf(-lmf[jj],     __log2f(va), LOG_HALF);
            rs[jj + 2] = fmaf(-lmf[jj + 2], __log2f(vb), LOG_HALF);
        }
        out4[oidx] = make_float4(rs[0], rs[1], rs[2], rs[3]);
    };

    // ---- software pipeline: A = even groups (ch 0-3), B = odd (ch 4-7) ----
    float4 pkA[4], pkB[4];
    float dyA[4], dyB[4], lmA[4], lmB[4];

    float4 xg0 = x4[idx4(0)];
    float4 xg1 = x4[idx4(1)];
    gather4(xg0, 0, pkA, dyA, lmA);
    float4 xg2 = x4[idx4(2)];

    #pragma unroll 1
    for (int g = 0; g < ng; g += 2) {
        gather4(xg1, 4, pkB, dyB, lmB);       // gather g+1
        xg1 = x4[idx4(g + 3)];                // prefetch x(g+3)
        mathstore(pkA, dyA, lmA, idx4(g));    // math+store g
        gather4(xg2, 0, pkA, dyA, lmA);       // gather g+2
        xg2 = x4[idx4(g + 4)];                // prefetch x(g+4)
        mathstore(pkB, dyB, lmB, idx4(g + 1));// math+store g+1
    }
}

extern "C" void kernel_launch(void* const* d_in, const int* in_sizes, int n_in,
                              void* d_out, int out_size, void* d_ws, size_t ws_size,
                              hipStream_t stream) {
    const float* x  = (const float*)d_in[0];
    const float* uw = (const float*)d_in[1];
    const float* uh = (const float*)d_in[2];
    const float* ud = (const float*)d_in[3];
    float* ws = (float*)d_ws;

    spline_precompute<<<NCH, NB, 0, stream>>>(uw, uh, ud, ws);

    const int npair = out_size / 8;   // 2,097,152 = 8 * 1024*256
    spline_main<<<1024, 256, 0, stream>>>(
        (const float4*)x, (float4*)d_out, ws, npair);
}

// Round 10
// 41.571 us; speedup vs baseline: 1.0216x; 1.0216x over previous
//
#include <hip/hip_runtime.h>
#include <math.h>

// Rational-quadratic spline inverse log-prob (Durkan et al.), inverse pass only.
// out = log(0.5) - where(inside, logabsdet, 0)
//
// ws/tab byte layout (20,592 B total):
//   edges @ 0     : 8ch x 129 f32 (cumheights; [.,128] = 1+1e-6 sentinel)
//   packh @ 4128  : 8ch x 129 f16x4 {delta, d0, T=d0+d1-2*delta, 0} (8 B)
//   hint  @ 12384 : 8ch x 1025 u8. slot width 2/1024 = 1.953e-3 < min bin
//     height 2e-3 => at most ONE knot per slot => 1-step fixup exact.
//     Entry [1024] handles xc == 1.0 (no slot clamp needed).
// Per element: 4 LDS ops (u8 hint -> read2_b32+b32 edges e0,e1,e2 -> b64 pack).
// KEY NUMERICS FIX vs R9: bin height h = e_{k2+1} - e_{k2} comes from the f32
// edges (so dy <= h EXACTLY -> root stays in [0,1]); only delta/d0/T are f16
// (multiplicative-only, rel 5e-4 -> ~2e-3 logdet error vs 0.114 threshold).

#define NB 128
#define NCH 8
#define NSLOT 1024
#define PACK_B 4128
#define HINT_B 12384
#define TAB_FLOATS 5148   // 20592 B staged

typedef float v2f __attribute__((ext_vector_type(2)));
typedef _Float16 h4 __attribute__((ext_vector_type(4)));

static __device__ inline unsigned short f2h(float v) {
    union { _Float16 h; unsigned short u; } c;
    c.h = (_Float16)v;
    return c.u;
}

__global__ __launch_bounds__(128) void spline_precompute(
    const float* __restrict__ uw, const float* __restrict__ uh,
    const float* __restrict__ ud, float* __restrict__ ws)
{
    const int c = blockIdx.x;   // channel
    const int i = threadIdx.x;  // bin
    __shared__ float red[128];
    __shared__ float scan[128];
    __shared__ float cum[129];
    __shared__ float wdt[128];
    __shared__ float sdv[129];
    const float DEFAULT_INIT = logf(expf(1.0f - 1e-3f) - 1.0f);

    // ---------------- widths: softmax(uw*10) -> sizes -> cumsum -> knots ----
    float v = uw[c * NB + i] * 10.0f;
    red[i] = v; __syncthreads();
    #pragma unroll
    for (int s = 64; s >= 1; s >>= 1) { if (i < s) red[i] = fmaxf(red[i], red[i + s]); __syncthreads(); }
    float ex = expf(v - red[0]);
    __syncthreads();
    red[i] = ex; __syncthreads();
    #pragma unroll
    for (int s = 64; s >= 1; s >>= 1) { if (i < s) red[i] += red[i + s]; __syncthreads(); }
    float sz = 1e-3f + (1.0f - 1e-3f * NB) * (ex / red[0]);
    __syncthreads();
    scan[i] = sz;
    for (int off = 1; off < NB; off <<= 1) {
        __syncthreads();
        float t = (i >= off) ? scan[i - off] : 0.0f;
        __syncthreads();
        scan[i] += t;
    }
    __syncthreads();
    if (i == 0) cum[0] = -1.0f;
    cum[i + 1] = (i == NB - 1) ? 1.0f : fmaf(2.0f, scan[i], -1.0f);
    __syncthreads();
    wdt[i] = cum[i + 1] - cum[i];
    __syncthreads();   // cum gets reused below

    // ---------------- heights: same pipeline on uh*10 ----------------------
    v = uh[c * NB + i] * 10.0f;
    red[i] = v; __syncthreads();
    #pragma unroll
    for (int s = 64; s >= 1; s >>= 1) { if (i < s) red[i] = fmaxf(red[i], red[i + s]); __syncthreads(); }
    ex = expf(v - red[0]);
    __syncthreads();
    red[i] = ex; __syncthreads();
    #pragma unroll
    for (int s = 64; s >= 1; s >>= 1) { if (i < s) red[i] += red[i + s]; __syncthreads(); }
    sz = 1e-3f + (1.0f - 1e-3f * NB) * (ex / red[0]);
    __syncthreads();
    scan[i] = sz;
    for (int off = 1; off < NB; off <<= 1) {
        __syncthreads();
        float t = (i >= off) ? scan[i - off] : 0.0f;
        __syncthreads();
        scan[i] += t;
    }
    __syncthreads();
    if (i == 0) cum[0] = -1.0f;
    cum[i + 1] = (i == NB - 1) ? 1.0f : fmaf(2.0f, scan[i], -1.0f);

    // ---------------- derivatives: MIN_D + softplus(pad(ud)) ---------------
    float u0 = (i == 0) ? DEFAULT_INIT : ud[c * (NB - 1) + i - 1];
    sdv[i] = 1e-3f + log1pf(expf(u0));
    if (i == NB - 1) sdv[NB] = 1e-3f + log1pf(expf(DEFAULT_INIT));
    __syncthreads();

    // ---------------- emit tables ------------------------------------------
    float hh  = cum[i + 1] - cum[i];
    float idl = hh / wdt[i];
    float d0v = sdv[i], d1v = sdv[i + 1];
    float Tv  = d0v + d1v - 2.0f * idl;
    const int o = c * 129 + i;

    ws[o] = cum[i];
    if (i == NB - 1) ws[c * 129 + NB] = 1.0f + 1e-6f;   // sentinel

    ushort4* g_pk = reinterpret_cast<ushort4*>(reinterpret_cast<char*>(ws) + PACK_B);
    g_pk[o] = make_ushort4(f2h(idl), f2h(d0v), f2h(Tv), 0);
    if (i == NB - 1)   // pad entry 128 (unreachable; keep memory defined)
        g_pk[o + 1] = make_ushort4(f2h(1.0f), f2h(1.0f), 0, 0);

    // hint[s] = max k in [0,127] with cum[k] <= slot_left (true bin = k or k+1)
    unsigned char* g_hint = reinterpret_cast<unsigned char*>(ws) + HINT_B;
    for (int s = i; s < NSLOT + 1; s += NB) {
        float left = (float)s * (2.0f / NSLOT) - 1.0f;
        int k = 0;
        #pragma unroll
        for (int st = 64; st >= 1; st >>= 1) {   // 64+...+1 = 127, stays in [0,127]
            int t = k + st;
            if (cum[t] <= left) k = t;
        }
        g_hint[c * (NSLOT + 1) + s] = (unsigned char)k;
    }
}

__global__ __launch_bounds__(256, 6) void spline_main(
    const float4* __restrict__ x4, float4* __restrict__ out4,
    const float* __restrict__ ws, int npair)
{
    __shared__ __align__(16) float tab[TAB_FLOATS];
    {
        float4* dst = reinterpret_cast<float4*>(tab);
        const float4* src = reinterpret_cast<const float4*>(ws);
        for (int t = threadIdx.x; t < TAB_FLOATS / 4; t += 256) dst[t] = src[t];
    }
    __syncthreads();
    const float* eg = tab;
    const h4* ph = reinterpret_cast<const h4*>(reinterpret_cast<const char*>(tab) + PACK_B);
    const unsigned char* hint = reinterpret_cast<const unsigned char*>(tab) + HINT_B;

    const float LOG_HALF = -0.6931471805599453f;
    const float LN2 = 0.6931471805599453f;
    const int tid = blockIdx.x * 256 + threadIdx.x;
    const int stride = gridDim.x * 256;

    float4 pfa, pfb;
    if (tid < npair) { pfa = x4[2 * tid]; pfb = x4[2 * tid + 1]; }

    for (int i = tid; i < npair; i += stride) {
        float4 xa = pfa, xb = pfb;
        int inx = i + stride;
        inx = (inx < npair) ? inx : i;          // safe redundant prefetch on last iter
        pfa = x4[2 * inx];
        pfb = x4[2 * inx + 1];

        float xs[8] = {xa.x, xa.y, xa.z, xa.w, xb.x, xb.y, xb.z, xb.w};

        // ---- phase 1: clamp (med3), slot, hint (8 independent u8 reads) ---
        float xq[8];
        int kk[8];
        #pragma unroll
        for (int j = 0; j < 8; ++j) {
            float xc = __builtin_amdgcn_fmed3f(xs[j], -1.0f, 1.0f);
            xq[j] = xc;
            int s = (int)fmaf(xc, (float)(NSLOT / 2), (float)(NSLOT / 2)); // [0,1024]
            kk[j] = hint[j * (NSLOT + 1) + s];
        }

        // ---- phase 2: edge triple reads (e_k, e_{k+1}, e_{k+2}) -----------
        // (k=127 e2 over-read lands in pack region: valid LDS, never selected)
        float e0[8], e1[8], e2[8];
        #pragma unroll
        for (int j = 0; j < 8; ++j) {
            const float* ej = eg + j * 129 + kk[j];
            e0[j] = ej[0];
            e1[j] = ej[1];
            e2[j] = ej[2];
        }

        // ---- phase 3: fixup; h from f32 edges; f16 pack reads (b64) -------
        h4 hv[8];
        float dyv[8], hb[8], lm[8];
        #pragma unroll
        for (int j = 0; j < 8; ++j) {
            bool adv = (e1[j] <= xq[j]);
            int k2 = kk[j] + (adv ? 1 : 0);
            float elo = adv ? e1[j] : e0[j];
            float ehi = adv ? e2[j] : e1[j];
            dyv[j] = xq[j] - elo;
            hb[j]  = ehi - elo;                      // dy <= h exactly (f32)
            lm[j] = (xs[j] == xq[j]) ? LN2 : 0.0f;   // inside <=> clamp no-op
            hv[j] = ph[j * 129 + k2];
        }

        // ---- phase 4: packed-f32 math (v_pk_*), pairs (j, j+4) ------------
        float rs[8];
        #pragma unroll
        for (int jj = 0; jj < 4; ++jj) {
            v2f dl = {(float)hv[jj].x, (float)hv[jj + 4].x};
            v2f d0 = {(float)hv[jj].y, (float)hv[jj + 4].y};
            v2f T  = {(float)hv[jj].z, (float)hv[jj + 4].z};
            v2f h  = {hb[jj],  hb[jj + 4]};
            v2f dy = {dyv[jj], dyv[jj + 4]};
            const v2f m4 = {-4.0f, -4.0f};
            const v2f zz = {0.0f, 0.0f};

            v2f dyt  = dy * T;
            v2f sdd  = dl - d0;
            v2f E    = sdd + sdd;
            v2f aa   = __builtin_elementwise_fma(h, sdd, dyt);  // dy*T + h*(dl-d0)
            v2f bb   = __builtin_elementwise_fma(h, d0, -dyt);  // h*d0 - dy*T
            v2f cc   = -dl * dy;
            v2f ac   = aa * cc;
            v2f disc = __builtin_elementwise_max(
                           __builtin_elementwise_fma(m4, ac, bb * bb), zz);
            v2f sq   = {__builtin_amdgcn_sqrtf(disc.x),
                        __builtin_amdgcn_sqrtf(disc.y)};
            v2f w    = -bb - sq;                    // root = u/w, u = 2c
            v2f u    = cc + cc;
            v2f w2   = w * w;
            v2f tu   = T * u;
            v2f t1   = __builtin_elementwise_fma(E, w, tu);     // T*u + E*w
            v2f num  = __builtin_elementwise_fma(t1, u, d0 * w2);
            v2f d2   = dl * dl;
            v2f numf = (num * w2) * d2;
            v2f wmu  = w - u;
            v2f denb = __builtin_elementwise_fma(tu, wmu, dl * w2);
            v2f den2 = denb * denb;

            float va = __fdividef(numf.x, den2.x);
            float vb = __fdividef(numf.y, den2.y);
            rs[jj]     = fmaf(-lm[jj],     __log2f(va), LOG_HALF);
            rs[jj + 4] = fmaf(-lm[jj + 4], __log2f(vb), LOG_HALF);
        }

        out4[2 * i]     = make_float4(rs[0], rs[1], rs[2], rs[3]);
        out4[2 * i + 1] = make_float4(rs[4], rs[5], rs[6], rs[7]);
    }
}

extern "C" void kernel_launch(void* const* d_in, const int* in_sizes, int n_in,
                              void* d_out, int out_size, void* d_ws, size_t ws_size,
                              hipStream_t stream) {
    const float* x  = (const float*)d_in[0];
    const float* uw = (const float*)d_in[1];
    const float* uh = (const float*)d_in[2];
    const float* ud = (const float*)d_in[3];
    float* ws = (float*)d_ws;

    spline_precompute<<<NCH, NB, 0, stream>>>(uw, uh, ud, ws);

    const int npair = out_size / 8;   // 2,097,152
    spline_main<<<1792, 256, 0, stream>>>(   // 7 blocks/CU target (20.6 KB LDS)
        (const float4*)x, (float4*)d_out, ws, npair);
}

// Round 13
// 40.692 us; speedup vs baseline: 1.0437x; 1.0216x over previous
//
#include <hip/hip_runtime.h>
#include <math.h>

// Rational-quadratic spline inverse log-prob (Durkan et al.), inverse pass only.
// out = log(0.5) + where(inside, log|dx/dy|, 0)
//
// IDENTITY (verified): implicit differentiation of a*th^2 + b*th + c = 0
// (a = dy*T + h*(dl-d0), b = h*d0 - dy*T, c = -dl*dy — the reference's exact
// coefficients) gives |dx/dy| = h*denom / (dl*sqrt(disc)), denom = dl +
// T*th*(1-th). der_num is never computed. Checks: th=0 -> 1/d0, th=1 -> 1/d1,
// linear case -> 1/dl; numeric test point matches denom^2/der_num.
//
// NUMERICS (R12 lesson): near steep knots d(log|dx/dy|)/d(position) ~ |T| up
// to ~800, so ALL position quantities (dy, h) must be f32-exact from the f32
// edges. Only the spline params are f16, packed CONSISTENTLY as {dl, d0, d1}
// with T derived in f32 (coherent spline perturbation, benign ~R10's 0.039).
//
// ws/tab byte layout (20,592 B total):
//   edges @ 0     : 8ch x 129 f32 (cumheights; [.,128] = 1+1e-6 sentinel)
//   packh @ 4128  : 8ch x 129 f16x4 {dl, d0, d1, 0} (8 B)
//   hint  @ 12384 : 8ch x 1025 u8. slot width 2/1024 = 1.953e-3 < min bin
//     height 2e-3 => at most ONE knot per slot => 1-step fixup exact.
// Per element: 4 LDS ops (u8 hint -> read2_b32 + b32 edges -> b64 pack).

#define NB 128
#define NCH 8
#define NSLOT 1024
#define PACK_B 4128
#define HINT_B 12384
#define TAB_FLOATS 5148   // 20592 B staged

typedef float v2f __attribute__((ext_vector_type(2)));
typedef _Float16 h4 __attribute__((ext_vector_type(4)));

static __device__ inline unsigned short f2h(float v) {
    union { _Float16 h; unsigned short u; } c;
    c.h = (_Float16)v;
    return c.u;
}

__global__ __launch_bounds__(128) void spline_precompute(
    const float* __restrict__ uw, const float* __restrict__ uh,
    const float* __restrict__ ud, float* __restrict__ ws)
{
    const int c = blockIdx.x;   // channel
    const int i = threadIdx.x;  // bin
    __shared__ float red[128];
    __shared__ float scan[128];
    __shared__ float cum[129];
    __shared__ float wdt[128];
    __shared__ float sdv[129];
    const float DEFAULT_INIT = logf(expf(1.0f - 1e-3f) - 1.0f);

    // ---------------- widths: softmax(uw*10) -> sizes -> cumsum -> knots ----
    float v = uw[c * NB + i] * 10.0f;
    red[i] = v; __syncthreads();
    #pragma unroll
    for (int s = 64; s >= 1; s >>= 1) { if (i < s) red[i] = fmaxf(red[i], red[i + s]); __syncthreads(); }
    float ex = expf(v - red[0]);
    __syncthreads();
    red[i] = ex; __syncthreads();
    #pragma unroll
    for (int s = 64; s >= 1; s >>= 1) { if (i < s) red[i] += red[i + s]; __syncthreads(); }
    float sz = 1e-3f + (1.0f - 1e-3f * NB) * (ex / red[0]);
    __syncthreads();
    scan[i] = sz;
    for (int off = 1; off < NB; off <<= 1) {
        __syncthreads();
        float t = (i >= off) ? scan[i - off] : 0.0f;
        __syncthreads();
        scan[i] += t;
    }
    __syncthreads();
    if (i == 0) cum[0] = -1.0f;
    cum[i + 1] = (i == NB - 1) ? 1.0f : fmaf(2.0f, scan[i], -1.0f);
    __syncthreads();
    wdt[i] = cum[i + 1] - cum[i];
    __syncthreads();   // cum gets reused below

    // ---------------- heights: same pipeline on uh*10 ----------------------
    v = uh[c * NB + i] * 10.0f;
    red[i] = v; __syncthreads();
    #pragma unroll
    for (int s = 64; s >= 1; s >>= 1) { if (i < s) red[i] = fmaxf(red[i], red[i + s]); __syncthreads(); }
    ex = expf(v - red[0]);
    __syncthreads();
    red[i] = ex; __syncthreads();
    #pragma unroll
    for (int s = 64; s >= 1; s >>= 1) { if (i < s) red[i] += red[i + s]; __syncthreads(); }
    sz = 1e-3f + (1.0f - 1e-3f * NB) * (ex / red[0]);
    __syncthreads();
    scan[i] = sz;
    for (int off = 1; off < NB; off <<= 1) {
        __syncthreads();
        float t = (i >= off) ? scan[i - off] : 0.0f;
        __syncthreads();
        scan[i] += t;
    }
    __syncthreads();
    if (i == 0) cum[0] = -1.0f;
    cum[i + 1] = (i == NB - 1) ? 1.0f : fmaf(2.0f, scan[i], -1.0f);

    // ---------------- derivatives: MIN_D + softplus(pad(ud)) ---------------
    float u0 = (i == 0) ? DEFAULT_INIT : ud[c * (NB - 1) + i - 1];
    sdv[i] = 1e-3f + log1pf(expf(u0));
    if (i == NB - 1) sdv[NB] = 1e-3f + log1pf(expf(DEFAULT_INIT));
    __syncthreads();

    // ---------------- emit tables ------------------------------------------
    float hh  = cum[i + 1] - cum[i];
    float idl = hh / wdt[i];
    const int o = c * 129 + i;

    ws[o] = cum[i];
    if (i == NB - 1) ws[c * 129 + NB] = 1.0f + 1e-6f;   // sentinel

    ushort4* g_pk = reinterpret_cast<ushort4*>(reinterpret_cast<char*>(ws) + PACK_B);
    g_pk[o] = make_ushort4(f2h(idl), f2h(sdv[i]), f2h(sdv[i + 1]), 0);
    if (i == NB - 1)   // pad entry 128 (unreachable; keep memory defined)
        g_pk[o + 1] = make_ushort4(f2h(1.0f), f2h(1.0f), f2h(1.0f), 0);

    // hint[s] = max k in [0,127] with cum[k] <= slot_left (true bin = k or k+1)
    unsigned char* g_hint = reinterpret_cast<unsigned char*>(ws) + HINT_B;
    for (int s = i; s < NSLOT + 1; s += NB) {
        float left = (float)s * (2.0f / NSLOT) - 1.0f;
        int k = 0;
        #pragma unroll
        for (int st = 64; st >= 1; st >>= 1) {   // 64+...+1 = 127, stays in [0,127]
            int t = k + st;
            if (cum[t] <= left) k = t;
        }
        g_hint[c * (NSLOT + 1) + s] = (unsigned char)k;
    }
}

__global__ __launch_bounds__(256, 6) void spline_main(
    const float4* __restrict__ x4, float4* __restrict__ out4,
    const float* __restrict__ ws, int npair)
{
    __shared__ __align__(16) float tab[TAB_FLOATS];
    {
        float4* dst = reinterpret_cast<float4*>(tab);
        const float4* src = reinterpret_cast<const float4*>(ws);
        for (int t = threadIdx.x; t < TAB_FLOATS / 4; t += 256) dst[t] = src[t];
    }
    __syncthreads();
    const float* eg = tab;
    const h4* ph = reinterpret_cast<const h4*>(reinterpret_cast<const char*>(tab) + PACK_B);
    const unsigned char* hint = reinterpret_cast<const unsigned char*>(tab) + HINT_B;

    const float LOG_HALF = -0.6931471805599453f;
    const float LN2 = 0.6931471805599453f;
    const int tid = blockIdx.x * 256 + threadIdx.x;
    const int stride = gridDim.x * 256;

    float4 pfa, pfb;
    if (tid < npair) { pfa = x4[2 * tid]; pfb = x4[2 * tid + 1]; }

    for (int i = tid; i < npair; i += stride) {
        float4 xa = pfa, xb = pfb;
        int inx = i + stride;
        inx = (inx < npair) ? inx : i;          // safe redundant prefetch on last iter
        pfa = x4[2 * inx];
        pfb = x4[2 * inx + 1];

        float xs[8] = {xa.x, xa.y, xa.z, xa.w, xb.x, xb.y, xb.z, xb.w};

        // ---- phase 1: clamp (med3), slot, hint (8 independent u8 reads) ---
        float xq[8];
        int kk[8];
        #pragma unroll
        for (int j = 0; j < 8; ++j) {
            float xc = __builtin_amdgcn_fmed3f(xs[j], -1.0f, 1.0f);
            xq[j] = xc;
            int s = (int)fmaf(xc, (float)(NSLOT / 2), (float)(NSLOT / 2)); // [0,1024]
            kk[j] = hint[j * (NSLOT + 1) + s];
        }

        // ---- phase 2: edge triple reads (e_k, e_{k+1}, e_{k+2}) -----------
        // (k=127 e2 over-read lands in pack region: valid LDS, never selected)
        float e0[8], e1[8], e2[8];
        #pragma unroll
        for (int j = 0; j < 8; ++j) {
            const float* ej = eg + j * 129 + kk[j];
            e0[j] = ej[0];
            e1[j] = ej[1];
            e2[j] = ej[2];
        }

        // ---- phase 3: fixup; dy, h f32-exact; f16 pack reads (b64) --------
        h4 hv[8];
        float dyv[8], hb[8], lm[8];
        #pragma unroll
        for (int j = 0; j < 8; ++j) {
            bool adv = (e1[j] <= xq[j]);
            int k2 = kk[j] + (adv ? 1 : 0);
            float elo = adv ? e1[j] : e0[j];
            float ehi = adv ? e2[j] : e1[j];
            dyv[j] = xq[j] - elo;                    // 0 <= dy <= h exactly
            hb[j]  = ehi - elo;
            lm[j] = (xs[j] == xq[j]) ? LN2 : 0.0f;   // inside <=> clamp no-op
            hv[j] = ph[j * 129 + k2];
        }

        // ---- phase 4: identity math, packed-f32 (v_pk_*), pairs (j, j+4) --
        // a = dy*T + h*(dl-d0), b = h*d0 - dy*T, cp = dl*dy (= -c),
        // disc = b^2 + 4*a*cp, t2 = b + sqrt(disc)  (theta = 2cp/t2),
        // denb = t2^2 * denom = dl*t2^2 + T*2cp*(t2-2cp),
        // |dx/dy| = h*denb / (dl*sqrt(disc)*t2^2).
        float rs[8];
        #pragma unroll
        for (int jj = 0; jj < 4; ++jj) {
            v2f dl = {(float)hv[jj].x, (float)hv[jj + 4].x};
            v2f d0 = {(float)hv[jj].y, (float)hv[jj + 4].y};
            v2f d1 = {(float)hv[jj].z, (float)hv[jj + 4].z};
            v2f h  = {hb[jj],  hb[jj + 4]};
            v2f dy = {dyv[jj], dyv[jj + 4]};
            const v2f m2 = {-2.0f, -2.0f};
            const v2f four = {4.0f, 4.0f};
            const v2f zz = {0.0f, 0.0f};

            v2f T    = __builtin_elementwise_fma(m2, dl, d0 + d1);  // consistent
            v2f dyt  = dy * T;
            v2f sdd  = dl - d0;
            v2f a    = __builtin_elementwise_fma(h, sdd, dyt);
            v2f b    = __builtin_elementwise_fma(h, d0, -dyt);
            v2f cp   = dl * dy;
            v2f ac   = a * cp;
            v2f disc = __builtin_elementwise_max(
                           __builtin_elementwise_fma(four, ac, b * b), zz);
            v2f sq   = {__builtin_amdgcn_sqrtf(disc.x),
                        __builtin_amdgcn_sqrtf(disc.y)};
            v2f t2   = b + sq;
            v2f uu   = cp + cp;
            v2f t2s  = t2 * t2;
            v2f tu   = T * uu;
            v2f tmu  = t2 - uu;
            v2f denb = __builtin_elementwise_fma(tu, tmu, dl * t2s);
            v2f numf = h * denb;
            v2f den  = (dl * sq) * t2s;

            float va = __fdividef(numf.x, den.x);
            float vb = __fdividef(numf.y, den.y);
            rs[jj]     = fmaf(lm[jj],     __log2f(va), LOG_HALF);
            rs[jj + 4] = fmaf(lm[jj + 4], __log2f(vb), LOG_HALF);
        }

        out4[2 * i]     = make_float4(rs[0], rs[1], rs[2], rs[3]);
        out4[2 * i + 1] = make_float4(rs[4], rs[5], rs[6], rs[7]);
    }
}

extern "C" void kernel_launch(void* const* d_in, const int* in_sizes, int n_in,
                              void* d_out, int out_size, void* d_ws, size_t ws_size,
                              hipStream_t stream) {
    const float* x  = (const float*)d_in[0];
    const float* uw = (const float*)d_in[1];
    const float* uh = (const float*)d_in[2];
    const float* ud = (const float*)d_in[3];
    float* ws = (float*)d_ws;

    spline_precompute<<<NCH, NB, 0, stream>>>(uw, uh, ud, ws);

    const int npair = out_size / 8;   // 2,097,152
    spline_main<<<1792, 256, 0, stream>>>(   // 7 blocks/CU (20.6 KB LDS)
        (const float4*)x, (float4*)d_out, ws, npair);
}

// Round 14
// 40.528 us; speedup vs baseline: 1.0479x; 1.0040x over previous
//
#include <hip/hip_runtime.h>
#include <math.h>

// Rational-quadratic spline inverse log-prob (Durkan et al.), inverse pass only.
// out = log(0.5) + where(inside, log|dx/dy|, 0)
//
// IDENTITY (R13, verified): implicit differentiation of a*th^2 + b*th + c = 0
// (a = dy*T + h*(dl-d0), b = h*d0 - dy*T, c = -dl*dy) gives
// |dx/dy| = h*denom / (dl*sqrt(disc)), denom = dl + T*th*(1-th).
//
// NUMERICS: all POSITION quantities (dy, h) are f32-exact (edges f32; h stored
// f32 in the pack, computed by the same subtraction as the edges). Spline
// params (dl, d0, T) are f16 — a coherent param perturbation only (~5e-4 rel,
// R13-passing class). The math consumes ONLY (dl, d0, T), so rounded T is a
// valid spline (no inconsistency channel).
//
// ws/tab byte layout (28,848 B staged):
//   edges @ 0     : 8ch x 129 f32 (cumheights; [.,128] = 1+1e-6 sentinel)
//   pack  @ 4128  : 8ch x 129 x 16 B {h f32, dl|d0 f16x2, T f16, pad}
//   hint  @ 20640 : 8ch x 1025 u8. slot width 2/1024 = 1.953e-3 < min bin
//     height 2e-3 => at most ONE knot per slot => 1-step fixup exact.
// Per element: 3 LDS ops (u8 hint -> read2_b32 edge pair -> b128 pack).

#define NB 128
#define NCH 8
#define NSLOT 1024
#define PACK_B 4128
#define HINT_B 20640
#define TAB_FLOATS 7212   // 28848 B staged (16B-multiple)

typedef float v2f __attribute__((ext_vector_type(2)));

static __device__ inline unsigned short f2h(float v) {
    union { _Float16 h; unsigned short u; } c;
    c.h = (_Float16)v;
    return c.u;
}
static __device__ inline float h16lo(unsigned u) {
    union { unsigned short s; _Float16 h; } c; c.s = (unsigned short)(u & 0xffffu);
    return (float)c.h;
}
static __device__ inline float h16hi(unsigned u) {
    union { unsigned short s; _Float16 h; } c; c.s = (unsigned short)(u >> 16);
    return (float)c.h;
}

__global__ __launch_bounds__(128) void spline_precompute(
    const float* __restrict__ uw, const float* __restrict__ uh,
    const float* __restrict__ ud, float* __restrict__ ws)
{
    const int c = blockIdx.x;   // channel
    const int i = threadIdx.x;  // bin
    __shared__ float red[128];
    __shared__ float scan[128];
    __shared__ float cum[129];
    __shared__ float wdt[128];
    __shared__ float sdv[129];
    const float DEFAULT_INIT = logf(expf(1.0f - 1e-3f) - 1.0f);

    // ---------------- widths: softmax(uw*10) -> sizes -> cumsum -> knots ----
    float v = uw[c * NB + i] * 10.0f;
    red[i] = v; __syncthreads();
    #pragma unroll
    for (int s = 64; s >= 1; s >>= 1) { if (i < s) red[i] = fmaxf(red[i], red[i + s]); __syncthreads(); }
    float ex = expf(v - red[0]);
    __syncthreads();
    red[i] = ex; __syncthreads();
    #pragma unroll
    for (int s = 64; s >= 1; s >>= 1) { if (i < s) red[i] += red[i + s]; __syncthreads(); }
    float sz = 1e-3f + (1.0f - 1e-3f * NB) * (ex / red[0]);
    __syncthreads();
    scan[i] = sz;
    for (int off = 1; off < NB; off <<= 1) {
        __syncthreads();
        float t = (i >= off) ? scan[i - off] : 0.0f;
        __syncthreads();
        scan[i] += t;
    }
    __syncthreads();
    if (i == 0) cum[0] = -1.0f;
    cum[i + 1] = (i == NB - 1) ? 1.0f : fmaf(2.0f, scan[i], -1.0f);
    __syncthreads();
    wdt[i] = cum[i + 1] - cum[i];
    __syncthreads();   // cum gets reused below

    // ---------------- heights: same pipeline on uh*10 ----------------------
    v = uh[c * NB + i] * 10.0f;
    red[i] = v; __syncthreads();
    #pragma unroll
    for (int s = 64; s >= 1; s >>= 1) { if (i < s) red[i] = fmaxf(red[i], red[i + s]); __syncthreads(); }
    ex = expf(v - red[0]);
    __syncthreads();
    red[i] = ex; __syncthreads();
    #pragma unroll
    for (int s = 64; s >= 1; s >>= 1) { if (i < s) red[i] += red[i + s]; __syncthreads(); }
    sz = 1e-3f + (1.0f - 1e-3f * NB) * (ex / red[0]);
    __syncthreads();
    scan[i] = sz;
    for (int off = 1; off < NB; off <<= 1) {
        __syncthreads();
        float t = (i >= off) ? scan[i - off] : 0.0f;
        __syncthreads();
        scan[i] += t;
    }
    __syncthreads();
    if (i == 0) cum[0] = -1.0f;
    cum[i + 1] = (i == NB - 1) ? 1.0f : fmaf(2.0f, scan[i], -1.0f);

    // ---------------- derivatives: MIN_D + softplus(pad(ud)) ---------------
    float u0 = (i == 0) ? DEFAULT_INIT : ud[c * (NB - 1) + i - 1];
    sdv[i] = 1e-3f + log1pf(expf(u0));
    if (i == NB - 1) sdv[NB] = 1e-3f + log1pf(expf(DEFAULT_INIT));
    __syncthreads();

    // ---------------- emit tables ------------------------------------------
    float hh  = cum[i + 1] - cum[i];     // SAME subtraction as main's e1-e0
    float idl = hh / wdt[i];
    float d0v = sdv[i], d1v = sdv[i + 1];
    float Tv  = d0v + d1v - 2.0f * idl;
    const int o = c * 129 + i;

    ws[o] = cum[i];
    if (i == NB - 1) ws[c * 129 + NB] = 1.0f + 1e-6f;   // sentinel

    uint4* g_pk = reinterpret_cast<uint4*>(reinterpret_cast<char*>(ws) + PACK_B);
    unsigned dld0 = (unsigned)f2h(idl) | ((unsigned)f2h(d0v) << 16);
    g_pk[o] = make_uint4(__float_as_uint(hh), dld0, (unsigned)f2h(Tv), 0u);
    if (i == NB - 1)   // pad entry 128 (unreachable; keep memory defined)
        g_pk[o + 1] = make_uint4(__float_as_uint(1.0f),
                                 (unsigned)f2h(1.0f) | ((unsigned)f2h(1.0f) << 16),
                                 0u, 0u);

    // hint[s] = max k in [0,127] with cum[k] <= slot_left (true bin = k or k+1)
    unsigned char* g_hint = reinterpret_cast<unsigned char*>(ws) + HINT_B;
    for (int s = i; s < NSLOT + 1; s += NB) {
        float left = (float)s * (2.0f / NSLOT) - 1.0f;
        int k = 0;
        #pragma unroll
        for (int st = 64; st >= 1; st >>= 1) {   // 64+...+1 = 127, stays in [0,127]
            int t = k + st;
            if (cum[t] <= left) k = t;
        }
        g_hint[c * (NSLOT + 1) + s] = (unsigned char)k;
    }
}

__global__ __launch_bounds__(256, 4) void spline_main(
    const float4* __restrict__ x4, float4* __restrict__ out4,
    const float* __restrict__ ws, int npair)
{
    __shared__ __align__(16) float tab[TAB_FLOATS];
    {
        float4* dst = reinterpret_cast<float4*>(tab);
        const float4* src = reinterpret_cast<const float4*>(ws);
        for (int t = threadIdx.x; t < TAB_FLOATS / 4; t += 256) dst[t] = src[t];
    }
    __syncthreads();
    const float* eg = tab;
    const uint4* pk4 = reinterpret_cast<const uint4*>(
        reinterpret_cast<const char*>(tab) + PACK_B);
    const unsigned char* hint = reinterpret_cast<const unsigned char*>(tab) + HINT_B;

    const float LOG_HALF = -0.6931471805599453f;
    const float LN2 = 0.6931471805599453f;
    const int tid = blockIdx.x * 256 + threadIdx.x;
    const int stride = gridDim.x * 256;

    float4 pfa, pfb;
    if (tid < npair) { pfa = x4[2 * tid]; pfb = x4[2 * tid + 1]; }

    for (int i = tid; i < npair; i += stride) {
        float4 xa = pfa, xb = pfb;
        int inx = i + stride;
        inx = (inx < npair) ? inx : i;          // safe redundant prefetch on last iter
        pfa = x4[2 * inx];
        pfb = x4[2 * inx + 1];

        float xs[8] = {xa.x, xa.y, xa.z, xa.w, xb.x, xb.y, xb.z, xb.w};

        // ---- phase 1: clamp (med3), slot, hint (8 independent u8 reads) ---
        float xq[8];
        int kk[8];
        #pragma unroll
        for (int j = 0; j < 8; ++j) {
            float xc = __builtin_amdgcn_fmed3f(xs[j], -1.0f, 1.0f);
            xq[j] = xc;
            int s = (int)fmaf(xc, (float)(NSLOT / 2), (float)(NSLOT / 2)); // [0,1024]
            kk[j] = hint[j * (NSLOT + 1) + s];
        }

        // ---- phase 2: edge pair reads (read2_b32: e_k, e_{k+1}) -----------
        float e0[8], e1[8];
        #pragma unroll
        for (int j = 0; j < 8; ++j) {
            const float* ej = eg + j * 129 + kk[j];
            e0[j] = ej[0];
            e1[j] = ej[1];
        }

        // ---- phase 3: fixup; dy f32-exact; b128 pack reads ----------------
        uint4 pr[8];
        float dyv[8], lm[8];
        #pragma unroll
        for (int j = 0; j < 8; ++j) {
            bool adv = (e1[j] <= xq[j]);
            int k2 = kk[j] + (adv ? 1 : 0);
            float elo = adv ? e1[j] : e0[j];
            dyv[j] = xq[j] - elo;                    // 0 <= dy <= h exactly
            lm[j] = (xs[j] == xq[j]) ? LN2 : 0.0f;   // inside <=> clamp no-op
            pr[j] = pk4[j * 129 + k2];               // {h, dl|d0, T, pad}
        }

        // ---- phase 4: identity math, packed-f32 (v_pk_*), pairs (j, j+4) --
        // a = dy*T + h*(dl-d0), b = h*d0 - dy*T, cp = dl*dy,
        // disc = b^2 + 4*a*cp, t2 = b + sqrt(disc)  (theta = 2cp/t2),
        // denb = t2^2*denom = dl*t2^2 + T*2cp*(t2-2cp),
        // |dx/dy| = h*denb / (dl*sqrt(disc)*t2^2).
        float rs[8];
        #pragma unroll
        for (int jj = 0; jj < 4; ++jj) {
            v2f h  = {__uint_as_float(pr[jj].x), __uint_as_float(pr[jj + 4].x)};
            v2f dl = {h16lo(pr[jj].y), h16lo(pr[jj + 4].y)};
            v2f d0 = {h16hi(pr[jj].y), h16hi(pr[jj + 4].y)};
            v2f T  = {h16lo(pr[jj].z), h16lo(pr[jj + 4].z)};
            v2f dy = {dyv[jj], dyv[jj + 4]};
            const v2f four = {4.0f, 4.0f};
            const v2f zz = {0.0f, 0.0f};

            v2f dyt  = dy * T;
            v2f sdd  = dl - d0;
            v2f a    = __builtin_elementwise_fma(h, sdd, dyt);
            v2f b    = __builtin_elementwise_fma(h, d0, -dyt);
            v2f cp   = dl * dy;
            v2f ac   = a * cp;
            v2f disc = __builtin_elementwise_max(
                           __builtin_elementwise_fma(four, ac, b * b), zz);
            v2f sq   = {__builtin_amdgcn_sqrtf(disc.x),
                        __builtin_amdgcn_sqrtf(disc.y)};
            v2f t2   = b + sq;
            v2f uu   = cp + cp;
            v2f t2s  = t2 * t2;
            v2f tu   = T * uu;
            v2f tmu  = t2 - uu;
            v2f denb = __builtin_elementwise_fma(tu, tmu, dl * t2s);
            v2f numf = h * denb;
            v2f den  = (dl * sq) * t2s;

            float va = __fdividef(numf.x, den.x);
            float vb = __fdividef(numf.y, den.y);
            rs[jj]     = fmaf(lm[jj],     __log2f(va), LOG_HALF);
            rs[jj + 4] = fmaf(lm[jj + 4], __log2f(vb), LOG_HALF);
        }

        out4[2 * i]     = make_float4(rs[0], rs[1], rs[2], rs[3]);
        out4[2 * i + 1] = make_float4(rs[4], rs[5], rs[6], rs[7]);
    }
}

extern "C" void kernel_launch(void* const* d_in, const int* in_sizes, int n_in,
                              void* d_out, int out_size, void* d_ws, size_t ws_size,
                              hipStream_t stream) {
    const float* x  = (const float*)d_in[0];
    const float* uw = (const float*)d_in[1];
    const float* uh = (const float*)d_in[2];
    const float* ud = (const float*)d_in[3];
    float* ws = (float*)d_ws;

    spline_precompute<<<NCH, NB, 0, stream>>>(uw, uh, ud, ws);

    const int npair = out_size / 8;   // 2,097,152 = 2048*256*4
    spline_main<<<2048, 256, 0, stream>>>(
        (const float4*)x, (float4*)d_out, ws, npair);
}

// Round 15
// 40.051 us; speedup vs baseline: 1.0603x; 1.0119x over previous
//
#include <hip/hip_runtime.h>
#include <math.h>

// Rational-quadratic spline inverse log-prob (Durkan et al.), inverse pass only.
// out = log(0.5) + where(inside, log|dx/dy|, 0)
//
// IDENTITY (R13): |dx/dy| = h*denom / (dl*sqrt(disc)), denom = dl + T*th*(1-th),
// from implicit differentiation of the inverse quadratic. der_num never computed.
//
// R15 KEY CHANGE — LDS BANK LAYOUT: the R14 pack was 16 B records (dword 4k ->
// banks {0,8,16,24}+lane -> ~8-way conflict on every gather, ~35 cyc/batch,
// making the LDS pipe a co-bottleneck with VALU). New pack = STRIDE-3-DWORD
// records {h f32, dl|d0 f16x2, T f16} at dword 3k: gcd(3,32)=1 spreads record
// starts over all 32 banks -> random-k gather ~2-way = free (m136).
//
// tab byte layout (24,608 B staged):
//   edges @ 0     : 8ch x 129 f32 (cumheights; [.,128] = 1+1e-6 sentinel)
//   pack  @ 4128  : 8ch x 128 x 12 B {h, dl|d0, T}
//   hint  @ 16416 : 8ch x 1024 u8 (s clamped to 1023; covers xc = 1.0)
// Per element: 4 LDS ops (u8 hint -> read2 edges -> read2+b32 pack), all
// conflict-free. Position math f32-exact; params f16-coherent (R13/R14 class).

#define NB 128
#define NCH 8
#define NSLOT 1024
#define PACK_B 4128
#define HINT_B 16416
#define TAB_FLOATS 6152   // 24,608 B

typedef float v2f __attribute__((ext_vector_type(2)));

static __device__ inline unsigned short f2h(float v) {
    union { _Float16 h; unsigned short u; } c;
    c.h = (_Float16)v;
    return c.u;
}
static __device__ inline float h16lo(unsigned u) {
    union { unsigned short s; _Float16 h; } c; c.s = (unsigned short)(u & 0xffffu);
    return (float)c.h;
}
static __device__ inline float h16hi(unsigned u) {
    union { unsigned short s; _Float16 h; } c; c.s = (unsigned short)(u >> 16);
    return (float)c.h;
}

__global__ __launch_bounds__(128) void spline_precompute(
    const float* __restrict__ uw, const float* __restrict__ uh,
    const float* __restrict__ ud, float* __restrict__ ws)
{
    const int c = blockIdx.x;   // channel
    const int i = threadIdx.x;  // bin
    __shared__ float red[128];
    __shared__ float scan[128];
    __shared__ float cum[129];
    __shared__ float wdt[128];
    __shared__ float sdv[129];
    const float DEFAULT_INIT = logf(expf(1.0f - 1e-3f) - 1.0f);

    // ---------------- widths: softmax(uw*10) -> sizes -> cumsum -> knots ----
    float v = uw[c * NB + i] * 10.0f;
    red[i] = v; __syncthreads();
    #pragma unroll
    for (int s = 64; s >= 1; s >>= 1) { if (i < s) red[i] = fmaxf(red[i], red[i + s]); __syncthreads(); }
    float ex = expf(v - red[0]);
    __syncthreads();
    red[i] = ex; __syncthreads();
    #pragma unroll
    for (int s = 64; s >= 1; s >>= 1) { if (i < s) red[i] += red[i + s]; __syncthreads(); }
    float sz = 1e-3f + (1.0f - 1e-3f * NB) * (ex / red[0]);
    __syncthreads();
    scan[i] = sz;
    for (int off = 1; off < NB; off <<= 1) {
        __syncthreads();
        float t = (i >= off) ? scan[i - off] : 0.0f;
        __syncthreads();
        scan[i] += t;
    }
    __syncthreads();
    if (i == 0) cum[0] = -1.0f;
    cum[i + 1] = (i == NB - 1) ? 1.0f : fmaf(2.0f, scan[i], -1.0f);
    __syncthreads();
    wdt[i] = cum[i + 1] - cum[i];
    __syncthreads();   // cum gets reused below

    // ---------------- heights: same pipeline on uh*10 ----------------------
    v = uh[c * NB + i] * 10.0f;
    red[i] = v; __syncthreads();
    #pragma unroll
    for (int s = 64; s >= 1; s >>= 1) { if (i < s) red[i] = fmaxf(red[i], red[i + s]); __syncthreads(); }
    ex = expf(v - red[0]);
    __syncthreads();
    red[i] = ex; __syncthreads();
    #pragma unroll
    for (int s = 64; s >= 1; s >>= 1) { if (i < s) red[i] += red[i + s]; __syncthreads(); }
    sz = 1e-3f + (1.0f - 1e-3f * NB) * (ex / red[0]);
    __syncthreads();
    scan[i] = sz;
    for (int off = 1; off < NB; off <<= 1) {
        __syncthreads();
        float t = (i >= off) ? scan[i - off] : 0.0f;
        __syncthreads();
        scan[i] += t;
    }
    __syncthreads();
    if (i == 0) cum[0] = -1.0f;
    cum[i + 1] = (i == NB - 1) ? 1.0f : fmaf(2.0f, scan[i], -1.0f);

    // ---------------- derivatives: MIN_D + softplus(pad(ud)) ---------------
    float u0 = (i == 0) ? DEFAULT_INIT : ud[c * (NB - 1) + i - 1];
    sdv[i] = 1e-3f + log1pf(expf(u0));
    if (i == NB - 1) sdv[NB] = 1e-3f + log1pf(expf(DEFAULT_INIT));
    __syncthreads();

    // ---------------- emit tables ------------------------------------------
    float hh  = cum[i + 1] - cum[i];     // SAME subtraction as main's e1-e0
    float idl = hh / wdt[i];
    float d0v = sdv[i], d1v = sdv[i + 1];
    float Tv  = d0v + d1v - 2.0f * idl;

    ws[c * 129 + i] = cum[i];
    if (i == NB - 1) ws[c * 129 + NB] = 1.0f + 1e-6f;   // sentinel

    unsigned* g_pk = reinterpret_cast<unsigned*>(reinterpret_cast<char*>(ws) + PACK_B);
    const int pw = (c * NB + i) * 3;
    g_pk[pw]     = __float_as_uint(hh);
    g_pk[pw + 1] = (unsigned)f2h(idl) | ((unsigned)f2h(d0v) << 16);
    g_pk[pw + 2] = (unsigned)f2h(Tv);

    // hint[s] = max k in [0,127] with cum[k] <= slot_left (true bin = k or k+1)
    unsigned char* g_hint = reinterpret_cast<unsigned char*>(ws) + HINT_B;
    for (int s = i; s < NSLOT; s += NB) {
        float left = (float)s * (2.0f / NSLOT) - 1.0f;
        int k = 0;
        #pragma unroll
        for (int st = 64; st >= 1; st >>= 1) {   // 64+...+1 = 127, stays in [0,127]
            int t = k + st;
            if (cum[t] <= left) k = t;
        }
        g_hint[c * NSLOT + s] = (unsigned char)k;
    }
}

__global__ __launch_bounds__(256, 6) void spline_main(
    const float4* __restrict__ x4, float4* __restrict__ out4,
    const float* __restrict__ ws, int npair)
{
    __shared__ __align__(16) float tab[TAB_FLOATS];
    {
        float4* dst = reinterpret_cast<float4*>(tab);
        const float4* src = reinterpret_cast<const float4*>(ws);
        for (int t = threadIdx.x; t < TAB_FLOATS / 4; t += 256) dst[t] = src[t];
    }
    __syncthreads();
    const float* eg = tab;
    const unsigned* pku = reinterpret_cast<const unsigned*>(
        reinterpret_cast<const char*>(tab) + PACK_B);
    const unsigned char* hint = reinterpret_cast<const unsigned char*>(tab) + HINT_B;

    const float LOG_HALF = -0.6931471805599453f;
    const float LN2 = 0.6931471805599453f;
    const int tid = blockIdx.x * 256 + threadIdx.x;
    const int stride = gridDim.x * 256;

    float4 pfa, pfb;
    if (tid < npair) { pfa = x4[2 * tid]; pfb = x4[2 * tid + 1]; }

    for (int i = tid; i < npair; i += stride) {
        float4 xa = pfa, xb = pfb;
        int inx = i + stride;
        inx = (inx < npair) ? inx : i;          // safe redundant prefetch on last iter
        pfa = x4[2 * inx];
        pfb = x4[2 * inx + 1];

        float xs[8] = {xa.x, xa.y, xa.z, xa.w, xb.x, xb.y, xb.z, xb.w};

        // ---- phase 1: clamp (med3), slot, hint (8 independent u8 reads) ---
        float xq[8];
        int kk[8];
        #pragma unroll
        for (int j = 0; j < 8; ++j) {
            float xc = __builtin_amdgcn_fmed3f(xs[j], -1.0f, 1.0f);
            xq[j] = xc;
            int s = (int)fmaf(xc, (float)(NSLOT / 2), (float)(NSLOT / 2));
            s = (s > NSLOT - 1) ? NSLOT - 1 : s;    // covers xc == 1.0
            kk[j] = hint[j * NSLOT + s];
        }

        // ---- phase 2: edge pair reads (read2_b32: e_k, e_{k+1}) -----------
        float e0[8], e1[8];
        #pragma unroll
        for (int j = 0; j < 8; ++j) {
            const float* ej = eg + j * 129 + kk[j];
            e0[j] = ej[0];
            e1[j] = ej[1];
        }

        // ---- phase 3: fixup; dy f32-exact; stride-3 pack reads ------------
        unsigned pw0[8], pw1[8], pw2[8];
        float dyv[8], lm[8];
        #pragma unroll
        for (int j = 0; j < 8; ++j) {
            bool adv = (e1[j] <= xq[j]);
            int k2 = kk[j] + (adv ? 1 : 0);          // <= 127 (sentinel blocks 128)
            float elo = adv ? e1[j] : e0[j];
            dyv[j] = xq[j] - elo;                    // 0 <= dy <= h exactly
            lm[j] = (xs[j] == xq[j]) ? LN2 : 0.0f;   // inside <=> clamp no-op
            const unsigned* p = pku + (j * NB + k2) * 3;   // bank-spread (stride 3)
            pw0[j] = p[0];                           // h (f32 bits)
            pw1[j] = p[1];                           // dl|d0 f16x2
            pw2[j] = p[2];                           // T f16
        }

        // ---- phase 4: identity math, packed-f32 (v_pk_*), pairs (j, j+4) --
        // a = dy*T + h*(dl-d0), b = h*d0 - dy*T, cp = dl*dy,
        // disc = b^2 + 4*a*cp, t2 = b + sqrt(disc)  (theta = 2cp/t2),
        // denb = t2^2*denom = dl*t2^2 + T*2cp*(t2-2cp),
        // log|dx/dy| = log2(h*denb) - log2(dl*sqrt(disc)*t2^2), scaled by ln2.
        float rs[8];
        #pragma unroll
        for (int jj = 0; jj < 4; ++jj) {
            v2f h  = {__uint_as_float(pw0[jj]), __uint_as_float(pw0[jj + 4])};
            v2f dl = {h16lo(pw1[jj]), h16lo(pw1[jj + 4])};
            v2f d0 = {h16hi(pw1[jj]), h16hi(pw1[jj + 4])};
            v2f T  = {h16lo(pw2[jj]), h16lo(pw2[jj + 4])};
            v2f dy = {dyv[jj], dyv[jj + 4]};
            const v2f four = {4.0f, 4.0f};
            const v2f zz = {0.0f, 0.0f};

            v2f dyt  = dy * T;
            v2f sdd  = dl - d0;
            v2f a    = __builtin_elementwise_fma(h, sdd, dyt);
            v2f b    = __builtin_elementwise_fma(h, d0, -dyt);
            v2f cp   = dl * dy;
            v2f ac   = a * cp;
            v2f disc = __builtin_elementwise_max(
                           __builtin_elementwise_fma(four, ac, b * b), zz);
            v2f sq   = {__builtin_amdgcn_sqrtf(disc.x),
                        __builtin_amdgcn_sqrtf(disc.y)};
            v2f t2   = b + sq;
            v2f uu   = cp + cp;
            v2f t2s  = t2 * t2;
            v2f tu   = T * uu;
            v2f tmu  = t2 - uu;
            v2f denb = __builtin_elementwise_fma(tu, tmu, dl * t2s);
            v2f numf = h * denb;
            v2f den  = (dl * sq) * t2s;

            // log-split: no division
            float la = __log2f(numf.x) - __log2f(den.x);
            float lb = __log2f(numf.y) - __log2f(den.y);
            rs[jj]     = fmaf(lm[jj],     la, LOG_HALF);
            rs[jj + 4] = fmaf(lm[jj + 4], lb, LOG_HALF);
        }

        out4[2 * i]     = make_float4(rs[0], rs[1], rs[2], rs[3]);
        out4[2 * i + 1] = make_float4(rs[4], rs[5], rs[6], rs[7]);
    }
}

extern "C" void kernel_launch(void* const* d_in, const int* in_sizes, int n_in,
                              void* d_out, int out_size, void* d_ws, size_t ws_size,
                              hipStream_t stream) {
    const float* x  = (const float*)d_in[0];
    const float* uw = (const float*)d_in[1];
    const float* uh = (const float*)d_in[2];
    const float* ud = (const float*)d_in[3];
    float* ws = (float*)d_ws;

    spline_precompute<<<NCH, NB, 0, stream>>>(uw, uh, ud, ws);

    const int npair = out_size / 8;   // 2,097,152 = 2048*256*4
    spline_main<<<2048, 256, 0, stream>>>(
        (const float4*)x, (float4*)d_out, ws, npair);
}

// Round 16
// 39.994 us; speedup vs baseline: 1.0619x; 1.0014x over previous
//
#include <hip/hip_runtime.h>
#include <math.h>

// Rational-quadratic spline inverse log-prob (Durkan et al.), inverse pass only.
// out = log(0.5) + where(inside, log|dx/dy|, 0)
//
// IDENTITY (R13): |dx/dy| = h*denom / (dl*sqrt(disc)), denom = dl + T*th*(1-th).
//
// R16 KEY CHANGE — 2-LEVEL LDS CHAIN: bin selection is now ARITHMETIC:
//   hint16[slot] = k | split<<7, split = quantized (1/512-slot) position of
//   knot e_{k+1} in the slot; k2 = k + (q > split), q = low 9 bits of
//   (xc+1)*2^18. No edges read before the record gather -> LDS chain is
//   hint16 -> record (2 levels, 3 instrs) instead of hint -> edges -> pack.
//   Mis-selection <= 1 quantum (3.8e-6) is safe: log|dx/dy| is CONTINUOUS at
//   knots (derivative-matched), error <= ~4e-3 << 0.114. dy = med3(xc-e_lo,0,h)
//   clamps both directions -> root in [0,1] exact (no NaN class).
//   "No knot in slot" encodes split=511 with strict >, never advances.
//
// Record = {e_lo f32, h f32, dl|d0 f16x2, T f16} @ stride-5 dwords (20 B):
//   gcd(5,32)=1 -> record starts spread over all 32 banks (conflict-light).
//   e_lo, h f32-exact (same subtractions as reference edges) — position math
//   stays f32; params f16-coherent (R13/R14/R15 passing class).
//
// tab byte layout (37,024 B staged):
//   rec    @ 0     : 8ch x 129 x 20 B (entry 128 = safe pad, unreachable)
//   hint16 @ 20640 : 8ch x 1024 u16

#define NB 128
#define NCH 8
#define NSLOT 1024
#define HINT_B 20640
#define TAB_FLOATS 9256   // 37,024 B

typedef float v2f __attribute__((ext_vector_type(2)));

static __device__ inline unsigned f2h(float v) {
    union { _Float16 h; unsigned short u; } c;
    c.h = (_Float16)v;
    return (unsigned)c.u;
}
static __device__ inline float h16lo(unsigned u) {
    union { unsigned short s; _Float16 h; } c; c.s = (unsigned short)(u & 0xffffu);
    return (float)c.h;
}
static __device__ inline float h16hi(unsigned u) {
    union { unsigned short s; _Float16 h; } c; c.s = (unsigned short)(u >> 16);
    return (float)c.h;
}

__global__ __launch_bounds__(128) void spline_precompute(
    const float* __restrict__ uw, const float* __restrict__ uh,
    const float* __restrict__ ud, float* __restrict__ ws)
{
    const int c = blockIdx.x;   // channel
    const int i = threadIdx.x;  // bin
    __shared__ float red[128];
    __shared__ float scan[128];
    __shared__ float cum[129];
    __shared__ float wdt[128];
    __shared__ float sdv[129];
    const float DEFAULT_INIT = logf(expf(1.0f - 1e-3f) - 1.0f);

    // ---------------- widths: softmax(uw*10) -> sizes -> cumsum -> knots ----
    float v = uw[c * NB + i] * 10.0f;
    red[i] = v; __syncthreads();
    #pragma unroll
    for (int s = 64; s >= 1; s >>= 1) { if (i < s) red[i] = fmaxf(red[i], red[i + s]); __syncthreads(); }
    float ex = expf(v - red[0]);
    __syncthreads();
    red[i] = ex; __syncthreads();
    #pragma unroll
    for (int s = 64; s >= 1; s >>= 1) { if (i < s) red[i] += red[i + s]; __syncthreads(); }
    float sz = 1e-3f + (1.0f - 1e-3f * NB) * (ex / red[0]);
    __syncthreads();
    scan[i] = sz;
    for (int off = 1; off < NB; off <<= 1) {
        __syncthreads();
        float t = (i >= off) ? scan[i - off] : 0.0f;
        __syncthreads();
        scan[i] += t;
    }
    __syncthreads();
    if (i == 0) cum[0] = -1.0f;
    cum[i + 1] = (i == NB - 1) ? 1.0f : fmaf(2.0f, scan[i], -1.0f);
    __syncthreads();
    wdt[i] = cum[i + 1] - cum[i];
    __syncthreads();   // cum gets reused below

    // ---------------- heights: same pipeline on uh*10 ----------------------
    v = uh[c * NB + i] * 10.0f;
    red[i] = v; __syncthreads();
    #pragma unroll
    for (int s = 64; s >= 1; s >>= 1) { if (i < s) red[i] = fmaxf(red[i], red[i + s]); __syncthreads(); }
    ex = expf(v - red[0]);
    __syncthreads();
    red[i] = ex; __syncthreads();
    #pragma unroll
    for (int s = 64; s >= 1; s >>= 1) { if (i < s) red[i] += red[i + s]; __syncthreads(); }
    sz = 1e-3f + (1.0f - 1e-3f * NB) * (ex / red[0]);
    __syncthreads();
    scan[i] = sz;
    for (int off = 1; off < NB; off <<= 1) {
        __syncthreads();
        float t = (i >= off) ? scan[i - off] : 0.0f;
        __syncthreads();
        scan[i] += t;
    }
    __syncthreads();
    if (i == 0) cum[0] = -1.0f;
    cum[i + 1] = (i == NB - 1) ? 1.0f : fmaf(2.0f, scan[i], -1.0f);

    // ---------------- derivatives: MIN_D + softplus(pad(ud)) ---------------
    float u0 = (i == 0) ? DEFAULT_INIT : ud[c * (NB - 1) + i - 1];
    sdv[i] = 1e-3f + log1pf(expf(u0));
    if (i == NB - 1) sdv[NB] = 1e-3f + log1pf(expf(DEFAULT_INIT));
    __syncthreads();

    // ---------------- emit tables ------------------------------------------
    float hh  = cum[i + 1] - cum[i];     // SAME subtraction class as reference
    float idl = hh / wdt[i];
    float d0v = sdv[i], d1v = sdv[i + 1];
    float Tv  = d0v + d1v - 2.0f * idl;

    unsigned* g_rec = reinterpret_cast<unsigned*>(ws);
    const int rw = (c * 129 + i) * 5;
    g_rec[rw]     = __float_as_uint(cum[i]);
    g_rec[rw + 1] = __float_as_uint(hh);
    g_rec[rw + 2] = f2h(idl) | (f2h(d0v) << 16);
    g_rec[rw + 3] = f2h(Tv);
    g_rec[rw + 4] = 0u;
    if (i == NB - 1) {   // pad entry 128 (unreachable; keep defined & safe)
        const int pw = (c * 129 + NB) * 5;
        g_rec[pw]     = __float_as_uint(1.0f);
        g_rec[pw + 1] = __float_as_uint(1.0f);
        g_rec[pw + 2] = f2h(1.0f) | (f2h(1.0f) << 16);
        g_rec[pw + 3] = 0u;
        g_rec[pw + 4] = 0u;
    }

    // hint16[s] = k | split<<7.  k = max bin with cum[k] <= slot_left.
    // split = clamp(ceil((cum[k+1]-left)*2^18) - 1, 0, 511); advance iff q>split.
    // No knot in slot -> X >= 512 -> split=511 -> never advances (strict >).
    unsigned short* g_hint = reinterpret_cast<unsigned short*>(
        reinterpret_cast<char*>(ws) + HINT_B);
    for (int s = i; s < NSLOT; s += NB) {
        float left = (float)s * (2.0f / NSLOT) - 1.0f;
        int k = 0;
        #pragma unroll
        for (int st = 64; st >= 1; st >>= 1) {   // 64+...+1 = 127, stays in [0,127]
            int t = k + st;
            if (cum[t] <= left) k = t;
        }
        float X = (cum[k + 1] - left) * 262144.0f;   // (e1-left)/slot_w * 512
        int split = (int)ceilf(X) - 1;
        split = split < 0 ? 0 : (split > 511 ? 511 : split);
        g_hint[c * NSLOT + s] = (unsigned short)(k | (split << 7));
    }
}

__global__ __launch_bounds__(256, 4) void spline_main(
    const float4* __restrict__ x4, float4* __restrict__ out4,
    const float* __restrict__ ws, int npair)
{
    __shared__ __align__(16) float tab[TAB_FLOATS];
    {
        float4* dst = reinterpret_cast<float4*>(tab);
        const float4* src = reinterpret_cast<const float4*>(ws);
        for (int t = threadIdx.x; t < TAB_FLOATS / 4; t += 256) dst[t] = src[t];
    }
    __syncthreads();
    const unsigned* rec = reinterpret_cast<const unsigned*>(tab);
    const unsigned short* hint = reinterpret_cast<const unsigned short*>(
        reinterpret_cast<const char*>(tab) + HINT_B);

    const float LOG_HALF = -0.6931471805599453f;
    const float LN2 = 0.6931471805599453f;
    const int tid = blockIdx.x * 256 + threadIdx.x;
    const int stride = gridDim.x * 256;

    float4 pfa, pfb;
    if (tid < npair) { pfa = x4[2 * tid]; pfb = x4[2 * tid + 1]; }

    for (int i = tid; i < npair; i += stride) {
        float4 xa = pfa, xb = pfb;
        int inx = i + stride;
        inx = (inx < npair) ? inx : i;          // safe redundant prefetch on last iter
        pfa = x4[2 * inx];
        pfb = x4[2 * inx + 1];

        float xs[8] = {xa.x, xa.y, xa.z, xa.w, xb.x, xb.y, xb.z, xb.w};

        // ---- phase 1: clamp, fused slot+frac, hint16 reads (8 independent) -
        float xq[8];
        int qv[8];
        unsigned hv[8];
        #pragma unroll
        for (int j = 0; j < 8; ++j) {
            float xc = __builtin_amdgcn_fmed3f(xs[j], -1.0f, 1.0f);
            xq[j] = xc;
            float g = fmaf(xc, 262144.0f, 262144.0f);    // (xc+1)*2^18
            int gi = (int)g;
            gi = gi > 524287 ? 524287 : gi;
            qv[j] = gi & 511;
            hv[j] = hint[j * NSLOT + (gi >> 9)];
        }

        // ---- phase 2: arithmetic bin select + record reads (2-level chain) -
        unsigned p0[8], p1[8], p2[8], p3[8];
        #pragma unroll
        for (int j = 0; j < 8; ++j) {
            int k2 = (int)(hv[j] & 127u) + ((qv[j] > (int)(hv[j] >> 7)) ? 1 : 0);
            const unsigned* p = rec + (j * 129 + k2) * 5;   // stride-5: bank-spread
            p0[j] = p[0];   // e_lo f32
            p1[j] = p[1];   // h    f32
            p2[j] = p[2];   // dl|d0 f16x2
            p3[j] = p[3];   // T f16
        }

        // ---- phase 3: identity math, packed-f32 pairs (j, j+4) -------------
        // a = dy*T + h*(dl-d0), b = h*d0 - dy*T, cp = dl*dy,
        // disc = b^2 + 4*a*cp, t2 = b + sqrt(disc)  (theta = 2cp/t2),
        // denb = t2^2*denom = dl*t2^2 + T*2cp*(t2-2cp),
        // log|dx/dy| = log2(h*denb) - log2(dl*sqrt(disc)*t2^2), scaled by ln2.
        float rs[8];
        #pragma unroll
        for (int jj = 0; jj < 4; ++jj) {
            v2f el = {__uint_as_float(p0[jj]), __uint_as_float(p0[jj + 4])};
            v2f h  = {__uint_as_float(p1[jj]), __uint_as_float(p1[jj + 4])};
            v2f dl = {h16lo(p2[jj]), h16lo(p2[jj + 4])};
            v2f d0 = {h16hi(p2[jj]), h16hi(p2[jj + 4])};
            v2f T  = {h16lo(p3[jj]), h16lo(p3[jj + 4])};
            v2f xv = {xq[jj], xq[jj + 4]};
            v2f xr = {xs[jj], xs[jj + 4]};
            const v2f four = {4.0f, 4.0f};
            const v2f zz = {0.0f, 0.0f};

            v2f dyr  = xv - el;
            v2f dy   = {__builtin_amdgcn_fmed3f(dyr.x, 0.0f, h.x),   // clamp to [0,h]
                        __builtin_amdgcn_fmed3f(dyr.y, 0.0f, h.y)};  // exact invariant
            v2f dyt  = dy * T;
            v2f sdd  = dl - d0;
            v2f a    = __builtin_elementwise_fma(h, sdd, dyt);
            v2f b    = __builtin_elementwise_fma(h, d0, -dyt);
            v2f cp   = dl * dy;
            v2f ac   = a * cp;
            v2f disc = __builtin_elementwise_max(
                           __builtin_elementwise_fma(four, ac, b * b), zz);
            v2f sq   = {__builtin_amdgcn_sqrtf(disc.x),
                        __builtin_amdgcn_sqrtf(disc.y)};
            v2f t2   = b + sq;
            v2f uu   = cp + cp;
            v2f t2s  = t2 * t2;
            v2f tu   = T * uu;
            v2f tmu  = t2 - uu;
            v2f denb = __builtin_elementwise_fma(tu, tmu, dl * t2s);
            v2f numf = h * denb;
            v2f den  = (dl * sq) * t2s;

            float la = __log2f(numf.x) - __log2f(den.x);
            float lb = __log2f(numf.y) - __log2f(den.y);
            float lma = (xr.x == xv.x) ? LN2 : 0.0f;   // inside <=> clamp no-op
            float lmb = (xr.y == xv.y) ? LN2 : 0.0f;
            rs[jj]     = fmaf(lma, la, LOG_HALF);
            rs[jj + 4] = fmaf(lmb, lb, LOG_HALF);
        }

        out4[2 * i]     = make_float4(rs[0], rs[1], rs[2], rs[3]);
        out4[2 * i + 1] = make_float4(rs[4], rs[5], rs[6], rs[7]);
    }
}

extern "C" void kernel_launch(void* const* d_in, const int* in_sizes, int n_in,
                              void* d_out, int out_size, void* d_ws, size_t ws_size,
                              hipStream_t stream) {
    const float* x  = (const float*)d_in[0];
    const float* uw = (const float*)d_in[1];
    const float* uh = (const float*)d_in[2];
    const float* ud = (const float*)d_in[3];
    float* ws = (float*)d_ws;

    spline_precompute<<<NCH, NB, 0, stream>>>(uw, uh, ud, ws);

    const int npair = out_size / 8;   // 2,097,152 = 2048*256*4
    spline_main<<<2048, 256, 0, stream>>>(
        (const float4*)x, (float4*)d_out, ws, npair);
}